// Round 10
// baseline (314.903 us; speedup 1.0000x reference)
//
#include <hip/hip_runtime.h>
#include <hip/hip_bf16.h>

// B=8, C=512, N=2048, P=256.
// Round 20: LDS-granularity occupancy experiment. R3 anomaly (50.7KB + grid
// 1024 -> still 2 blocks/CU) is explained if LDS allocates in 8KB granules:
// (48KB, 56KB] -> 56KB -> floor(160/56)=2. Target EXACTLY 48KB:
//   - Pw: padded [4][16][136] (17,408B) -> per-wave [16][128] + granule-XOR
//     swizzle (16,384B), af-read conflict-free.
//   - PV reverted to per-wave tiling (16q x 256p; P/alpha wave-private) ->
//     Aly deleted (R3 measured square-PV neutral; per-wave drops a barrier,
//     costs ~144 bg reads/tile ~ 2us).
//   - LDS = FG 32,768 + Pw 16,384 = 49,152B = 48KB exactly -> 3 blocks/CU.
//   - kh=4 (grid 1024) to feed 3 resident blocks; 4-way merge (R2's, proven).
//   - prep_weights: split_w2 + 2x cast fused into one launch.
// Predicted: LDS_Block_Size 49,152; Occupancy 19.6 -> ~29 (DIAGNOSTIC);
// fused 101 -> ~89; merge 7 -> 11; total 265.6 -> ~255. If occupancy pins at
// 20%, granularity theory dead -> plateau confirmed.

typedef __attribute__((ext_vector_type(8))) short short8;
typedef __attribute__((ext_vector_type(4))) float floatx4;

// ---------------- bf16 helpers ----------------
__device__ __forceinline__ unsigned short f2bf(float v) {
    __hip_bfloat16 h = __float2bfloat16(v);
    return *(unsigned short*)&h;
}
__device__ __forceinline__ float bf2f(unsigned short u) {
    __hip_bfloat16 h;
    *(unsigned short*)&h = u;
    return __bfloat162float(h);
}

// async global->LDS 16B per lane (dest must be wave-linear: base + lane*16)
__device__ __forceinline__ void gl16(const unsigned short* g, unsigned short* l) {
    __builtin_amdgcn_global_load_lds(
        (const __attribute__((address_space(1))) unsigned int*)g,
        (__attribute__((address_space(3))) unsigned int*)l, 16, 0, 0);
}

// transpose + hi/lo split: X [R][N] fp32 -> Thi/Tlo [N][R] bf16 (batched over z)
// v2: 32r x 128n macro-tile, float4 loads, conflict-free LDS, short8 stores.
__global__ __launch_bounds__(256) void transpose_split(
    const float* __restrict__ X, unsigned short* __restrict__ Thi,
    unsigned short* __restrict__ Tlo, int R, int N)
{
    X   += (long)blockIdx.z * R * N;
    Thi += (long)blockIdx.z * N * R;
    Tlo += (long)blockIdx.z * N * R;
    __shared__ float s[32][133];
    const int t = threadIdx.x;
    const int n0 = blockIdx.x * 128, r0 = blockIdx.y * 32;
    const int nf = (t & 31) * 4, rf = t >> 5;
#pragma unroll
    for (int rr = 0; rr < 4; ++rr) {
        const int row = rf + rr * 8;
        const float4 v = *(const float4*)&X[(long)(r0 + row) * N + n0 + nf];
        s[row][nf]     = v.x;
        s[row][nf + 1] = v.y;
        s[row][nf + 2] = v.z;
        s[row][nf + 3] = v.w;
    }
    __syncthreads();
    const int n = t >> 1, rs = (t & 1) * 16;
    short8 h0, h1, l0, l1;
#pragma unroll
    for (int j = 0; j < 8; ++j) {
        const float v = s[rs + j][n];
        const unsigned short h = f2bf(v);
        h0[j] = (short)h;
        l0[j] = (short)f2bf(v - bf2f(h));
    }
#pragma unroll
    for (int j = 0; j < 8; ++j) {
        const float v = s[rs + 8 + j][n];
        const unsigned short h = f2bf(v);
        h1[j] = (short)h;
        l1[j] = (short)f2bf(v - bf2f(h));
    }
    const long ob = (long)(n0 + n) * R + r0 + rs;
    *(short8*)&Thi[ob]     = h0;
    *(short8*)&Thi[ob + 8] = h1;
    *(short8*)&Tlo[ob]     = l0;
    *(short8*)&Tlo[ob + 8] = l1;
}

// fused weight prep: [Wth;Wph] hi/lo split + Wg/Wz bf16 casts. grid = 2PC/256.
__global__ __launch_bounds__(256) void prep_weights(
    const float* __restrict__ Wth, const float* __restrict__ Wph,
    const float* __restrict__ Wg,  const float* __restrict__ Wz,
    unsigned short* __restrict__ Whi, unsigned short* __restrict__ Wlo,
    unsigned short* __restrict__ WgB, unsigned short* __restrict__ WzB, int PC)
{
    const int i = blockIdx.x * 256 + threadIdx.x;
    {
        const float v = (i < PC) ? Wth[i] : Wph[i - PC];
        const unsigned short hi = f2bf(v);
        Whi[i] = hi;
        Wlo[i] = f2bf(v - bf2f(hi));
    }
    if (i < PC / 4) {
        const float4 v = *(const float4*)&Wg[i * 4];
        ushort4 o;
        o.x = f2bf(v.x); o.y = f2bf(v.y); o.z = f2bf(v.z); o.w = f2bf(v.w);
        *(ushort4*)&WgB[i * 4] = o;
    } else if (i < PC / 2) {
        const int j = i - PC / 4;
        const float4 v = *(const float4*)&Wz[j * 4];
        ushort4 o;
        o.x = f2bf(v.x); o.y = f2bf(v.y); o.z = f2bf(v.z); o.w = f2bf(v.w);
        *(ushort4*)&WzB[j * 4] = o;
    }
}

// ---------------- MFMA GEMM (async global_load_lds, double-buffered) ----------
#define BK 32

template <bool SPLIT, int OUTMODE, int FM, int FN, bool XYSWAP>
__global__ __launch_bounds__(256) void mfma_gemm(
    const unsigned short* __restrict__ Ahi, const unsigned short* __restrict__ Alo,
    const unsigned short* __restrict__ Bhi, const unsigned short* __restrict__ Blo,
    void* __restrict__ Cout, void* __restrict__ Cout2,
    int K, int lda, int ldb, int ldc,
    long sA, long sB, long sC,
    float* __restrict__ S1, float* __restrict__ S2)
{
    constexpr int MTM = FM * 32, MTN = FN * 32;
    constexpr int SA = FM / 2, SB = FN / 2;
    constexpr int ASZ = MTM * BK, BSZ = MTN * BK;

    Ahi += (long)blockIdx.z * sA;
    Bhi += (long)blockIdx.z * sB;
    if (SPLIT) { Alo += (long)blockIdx.z * sA; Blo += (long)blockIdx.z * sB; }
    float* Cf = (float*)Cout + (long)blockIdx.z * sC;
    unsigned short* Ch = (unsigned short*)Cout + (long)blockIdx.z * sC;
    unsigned short* Cl = (unsigned short*)Cout2 + (long)blockIdx.z * sC;

    __shared__ unsigned short AsH[2 * ASZ], BsH[2 * BSZ];
    __shared__ unsigned short AsL[SPLIT ? 2 * ASZ : 8], BsL[SPLIT ? 2 * BSZ : 8];

    const int tid = threadIdx.x;
    const int wid = tid >> 6, lane = tid & 63;
    const int wm = (wid >> 1) * (FM * 16), wn = (wid & 1) * (FN * 16);
    const int l15 = lane & 15, quad = lane >> 4;
    const int m0 = (XYSWAP ? blockIdx.x : blockIdx.y) * MTM;
    const int n0 = (XYSWAP ? blockIdx.y : blockIdx.x) * MTN;

    int arow[SA], acol[SA], brow[SB], bcol[SB];
#pragma unroll
    for (int t = 0; t < SA; ++t) {
        const int gid = t * 256 + tid;
        arow[t] = gid >> 2; acol[t] = (gid & 3) * 8;
    }
#pragma unroll
    for (int t = 0; t < SB; ++t) {
        const int gid = t * 256 + tid;
        brow[t] = gid >> 2; bcol[t] = (gid & 3) * 8;
    }

    auto stage = [&](int k0, int buf) {
#pragma unroll
        for (int t = 0; t < SA; ++t) {
            const long o = (long)(m0 + arow[t]) * lda + k0 + acol[t];
            const int d = buf * ASZ + (t * 256 + tid) * 8;
            gl16(&Ahi[o], &AsH[d]);
            if (SPLIT) gl16(&Alo[o], &AsL[d]);
        }
#pragma unroll
        for (int t = 0; t < SB; ++t) {
            const long o = (long)(n0 + brow[t]) * ldb + k0 + bcol[t];
            const int d = buf * BSZ + (t * 256 + tid) * 8;
            gl16(&Bhi[o], &BsH[d]);
            if (SPLIT) gl16(&Blo[o], &BsL[d]);
        }
    };

    floatx4 acc[FM][FN];
#pragma unroll
    for (int i = 0; i < FM; ++i)
#pragma unroll
        for (int j = 0; j < FN; ++j) acc[i][j] = (floatx4){0.f, 0.f, 0.f, 0.f};

    const int iters = K / BK;
    stage(0, 0);
    __syncthreads();

    for (int it = 0; it < iters; ++it) {
        const int cur = it & 1;
        if (it + 1 < iters) stage((it + 1) * BK, cur ^ 1);

        short8 ah[FM], bh[FN], al[SPLIT ? FM : 1], bl[SPLIT ? FN : 1];
#pragma unroll
        for (int i = 0; i < FM; ++i) {
            ah[i] = *(const short8*)&AsH[cur * ASZ + (wm + i * 16 + l15) * BK + quad * 8];
            if (SPLIT) al[i] = *(const short8*)&AsL[cur * ASZ + (wm + i * 16 + l15) * BK + quad * 8];
        }
#pragma unroll
        for (int j = 0; j < FN; ++j) {
            bh[j] = *(const short8*)&BsH[cur * BSZ + (wn + j * 16 + l15) * BK + quad * 8];
            if (SPLIT) bl[j] = *(const short8*)&BsL[cur * BSZ + (wn + j * 16 + l15) * BK + quad * 8];
        }
#pragma unroll
        for (int i = 0; i < FM; ++i)
#pragma unroll
            for (int j = 0; j < FN; ++j) {
                acc[i][j] = __builtin_amdgcn_mfma_f32_16x16x32_bf16(ah[i], bh[j], acc[i][j], 0, 0, 0);
                if (SPLIT) {
                    acc[i][j] = __builtin_amdgcn_mfma_f32_16x16x32_bf16(ah[i], bl[j], acc[i][j], 0, 0, 0);
                    acc[i][j] = __builtin_amdgcn_mfma_f32_16x16x32_bf16(al[i], bh[j], acc[i][j], 0, 0, 0);
                }
            }

        __syncthreads();
    }

#pragma unroll
    for (int i = 0; i < FM; ++i)
#pragma unroll
        for (int j = 0; j < FN; ++j) {
            const int m = m0 + wm + i * 16 + quad * 4;
            const int n = n0 + wn + j * 16 + l15;
#pragma unroll
            for (int r = 0; r < 4; ++r) {
                const float v = acc[i][j][r];
                const long idx = (long)(m + r) * ldc + n;
                if (OUTMODE == 0) {
                    Cf[idx] = v;
                } else if (OUTMODE == 1 || OUTMODE == 3) {
                    Ch[idx] = f2bf(v);
                } else {
                    const unsigned short hi = f2bf(v);
                    Ch[idx] = hi;
                    Cl[idx] = f2bf(v - bf2f(hi));
                }
            }
        }

    if (OUTMODE == 3) {
        const int slot = (blockIdx.z * gridDim.x + blockIdx.x) * 2 + (wn >> 6);
#pragma unroll
        for (int i = 0; i < FM; ++i)
#pragma unroll
            for (int r = 0; r < 4; ++r) {
                float s = 0.f, q = 0.f;
#pragma unroll
                for (int j = 0; j < FN; ++j) {
                    const float v = acc[i][j][r];
                    s += v; q += v * v;
                }
#pragma unroll
                for (int msk = 1; msk < 16; msk <<= 1) {
                    s += __shfl_xor(s, msk, 64);
                    q += __shfl_xor(q, msk, 64);
                }
                if (l15 == 0) {
                    const int row = m0 + wm + i * 16 + quad * 4 + r;
                    S1[(long)row * 256 + slot] = s;
                    S2[(long)row * 256 + slot] = q;
                }
            }
    }
}

// ---------------- fused scores+softmax+y v7 (48KB LDS, per-wave PV, kh=4) ----
// 1024 blocks (b = id&7, kh = (id>>3)&3, qt = id>>5), 4 waves.
// S phase: as R5 (wave owns 16q x 128keys; half-column dbuf, 1 barrier/chunk).
// Softmax + P + PV fully wave-private: Pw per-wave [16][128] swizzled;
// oacc = 16q x 256p per wave. LDS = FG 32,768 + Pw 16,384 = 49,152B = 48KB.

// swizzled short-offset into a [rows][64-short] tile: 16B slot ^= row&7
__device__ __forceinline__ int swz64(int row, int slot) {
    return (row << 6) + (((slot ^ row) & 7) << 3);
}
// swizzled granule-base (shorts) into a [16][128-short] P tile; g in 0..15
__device__ __forceinline__ int swzP(int row, int g) {
    return (row << 7) + (((g & 8) | ((g ^ row) & 7)) << 3);
}

__global__ __launch_bounds__(256, 2) void fused_attn(
    const unsigned short* __restrict__ thphH,
    const unsigned short* __restrict__ thphL,
    const unsigned short* __restrict__ gbf,
    float* __restrict__ yp,       // [4][B][N][P] fp32 partials (self-normalized)
    float2* __restrict__ ml)      // [4][B*N] {m, l}
{
    const int N = 2048, P = 256, P2 = 512;
    const int id = blockIdx.x;
    const int b  = id & 7;            // XCD-locality heuristic
    const int kh = (id >> 3) & 3;     // key quarter
    const int qt = id >> 5;           // 0..31
    const int q0 = qt * 64;

    const unsigned short* thB = thphH + (long)b * N * P2;
    const unsigned short* tlB = thphL + (long)b * N * P2;
    const unsigned short* gB  = gbf   + (long)b * P * N;
    float*  ypB = yp + (long)kh * (8L * N * P) + (long)b * N * P;
    float2* mlB = ml + (long)kh * (8L * N) + (long)b * N;

    // phi hi/lo and G share the same LDS (disjoint phases / halves, fenced)
    __shared__ unsigned short FG[2 * 128 * 64];       // 32,768 B
    unsigned short* Fh = FG;                          // [128][64] swizzled
    unsigned short* Fl = FG + 128 * 64;
    unsigned short* Gs = FG;                          // [256][64] swizzled
    __shared__ unsigned short Pw[4 * 16 * 128];       // per-wave [16][128] swz

    const int tid = threadIdx.x;
    const int wid = tid >> 6, lane = tid & 63;
    const int l15 = lane & 15, quad = lane >> 4;
    unsigned short* Pwv = Pw + wid * 16 * 128;

    // theta fragments in registers: wave rows [q0+wid*16, +16), A m = l15
    short8 tHr[8], tLr[8];
    {
        const unsigned short* t1 = thB + (long)(q0 + wid * 16 + l15) * P2;
        const unsigned short* t2 = tlB + (long)(q0 + wid * 16 + l15) * P2;
#pragma unroll
        for (int kt = 0; kt < 8; ++kt) {
            tHr[kt] = *(const short8*)&t1[kt * 32 + quad * 8];
            tLr[kt] = *(const short8*)&t2[kt * 32 + quad * 8];
        }
    }

    float mrun[4], lrun[4];
#pragma unroll
    for (int r = 0; r < 4; ++r) { mrun[r] = -1e30f; lrun[r] = 0.f; }

    // oacc[pj]: rows q0+wid*16+quad*4+r, cols pj*16+l15 (wave-private)
    floatx4 oacc[16];
#pragma unroll
    for (int p = 0; p < 16; ++p) oacc[p] = (floatx4){0.f, 0.f, 0.f, 0.f};

    // staging: prow4 = tid>>2 (0..63), lslot = tid&3 (16B granule in 32-short half)
    const int prow4 = tid >> 2, lslot = tid & 3;
    short8 pfH[2][2], pfL[2][2];
    short8 pg[2][4];

    for (int mt = 0; mt < 4; ++mt) {
        const int m0 = kh * 512 + mt * 128;

        // ---- S phase: 8 chunks of 32 c, half-column dbuf (as R5) ----
        floatx4 sacc[8];
#pragma unroll
        for (int j = 0; j < 8; ++j) sacc[j] = (floatx4){0.f, 0.f, 0.f, 0.f};

#pragma unroll
        for (int s = 0; s < 2; ++s) {
            const long o = (long)(m0 + s * 64 + prow4) * P2 + P + 0 * 32 + lslot * 8;
            pfH[0][s] = *(const short8*)&thB[o];
            pfL[0][s] = *(const short8*)&tlB[o];
        }
#pragma unroll
        for (int s = 0; s < 2; ++s) {
            const int row = s * 64 + prow4;
            *(short8*)&Fh[swz64(row, lslot)] = pfH[0][s];
            *(short8*)&Fl[swz64(row, lslot)] = pfL[0][s];
        }
#pragma unroll
        for (int s = 0; s < 2; ++s) {
            const long o = (long)(m0 + s * 64 + prow4) * P2 + P + 1 * 32 + lslot * 8;
            pfH[1][s] = *(const short8*)&thB[o];
            pfL[1][s] = *(const short8*)&tlB[o];
        }
        __syncthreads();

#pragma unroll
        for (int kc = 0; kc < 8; ++kc) {
            if (kc < 6) {
#pragma unroll
                for (int s = 0; s < 2; ++s) {
                    const long o = (long)(m0 + s * 64 + prow4) * P2 + P + (kc + 2) * 32 + lslot * 8;
                    pfH[kc & 1][s] = *(const short8*)&thB[o];
                    pfL[kc & 1][s] = *(const short8*)&tlB[o];
                }
            }
            const short8 aH = tHr[kc];
            const short8 aL = tLr[kc];
            const int half = (kc & 1) * 4;
            __builtin_amdgcn_s_setprio(1);
#pragma unroll
            for (int j = 0; j < 8; ++j) {
                const int ro = swz64(j * 16 + l15, half + quad);
                const short8 bh = *(const short8*)&Fh[ro];
                const short8 bl = *(const short8*)&Fl[ro];
                sacc[j] = __builtin_amdgcn_mfma_f32_16x16x32_bf16(aH, bh, sacc[j], 0, 0, 0);
                sacc[j] = __builtin_amdgcn_mfma_f32_16x16x32_bf16(aH, bl, sacc[j], 0, 0, 0);
                sacc[j] = __builtin_amdgcn_mfma_f32_16x16x32_bf16(aL, bh, sacc[j], 0, 0, 0);
            }
            __builtin_amdgcn_s_setprio(0);
            if (kc < 7) {
                const int wh = ((kc + 1) & 1) * 4;
#pragma unroll
                for (int s = 0; s < 2; ++s) {
                    const int row = s * 64 + prow4;
                    *(short8*)&Fh[swz64(row, wh + lslot)] = pfH[(kc + 1) & 1][s];
                    *(short8*)&Fl[swz64(row, wh + lslot)] = pfL[(kc + 1) & 1][s];
                }
            }
            __syncthreads();
        }

        // ---- online softmax (wave-private; rows = quad*4+r) ----
        float alpha[4];
#pragma unroll
        for (int r = 0; r < 4; ++r) {
            float v = sacc[0][r];
#pragma unroll
            for (int j = 1; j < 8; ++j) v = fmaxf(v, sacc[j][r]);
            v = fmaxf(v, __shfl_xor(v, 1, 64));
            v = fmaxf(v, __shfl_xor(v, 2, 64));
            v = fmaxf(v, __shfl_xor(v, 4, 64));
            v = fmaxf(v, __shfl_xor(v, 8, 64));
            const float mo = mrun[r];
            const float mn = fmaxf(mo, v);
            mrun[r] = mn;
            alpha[r] = __expf(mo - mn);
        }
        float lpart[4] = {0.f, 0.f, 0.f, 0.f};
#pragma unroll
        for (int j = 0; j < 8; ++j)
#pragma unroll
            for (int r = 0; r < 4; ++r) {
                const float p = __expf(sacc[j][r] - mrun[r]);
                const int row = quad * 4 + r;
                const int g = j * 2 + (l15 >> 3);
                Pwv[swzP(row, g) + (l15 & 7)] = f2bf(p);
                lpart[r] += p;
            }
#pragma unroll
        for (int r = 0; r < 4; ++r) {
            float s = lpart[r];
            s += __shfl_xor(s, 1, 64);
            s += __shfl_xor(s, 2, 64);
            s += __shfl_xor(s, 4, 64);
            s += __shfl_xor(s, 8, 64);
            lrun[r] = lrun[r] * alpha[r] + s;
        }

        // rescale prior O (wave-private alphas)
        {
            const int noresc = (alpha[0] == 1.f) & (alpha[1] == 1.f) &
                               (alpha[2] == 1.f) & (alpha[3] == 1.f);
            if (!__all(noresc)) {
#pragma unroll
                for (int p = 0; p < 16; ++p)
#pragma unroll
                    for (int r = 0; r < 4; ++r) oacc[p][r] *= alpha[r];
            }
        }

        // ---- PV phase: per-wave tiling (16q x 256p), 4 chunks of 32 keys ----
#pragma unroll
        for (int s = 0; s < 4; ++s)
            pg[0][s] = *(const short8*)&gB[(long)(s * 64 + prow4) * N + m0 + 0 * 32 + lslot * 8];
#pragma unroll
        for (int s = 0; s < 4; ++s)
            *(short8*)&Gs[swz64(s * 64 + prow4, lslot)] = pg[0][s];
#pragma unroll
        for (int s = 0; s < 4; ++s)
            pg[1][s] = *(const short8*)&gB[(long)(s * 64 + prow4) * N + m0 + 1 * 32 + lslot * 8];
        __syncthreads();   // G0 visible

#pragma unroll
        for (int mc = 0; mc < 4; ++mc) {
            if (mc < 2) {
#pragma unroll
                for (int s = 0; s < 4; ++s)
                    pg[mc & 1][s] = *(const short8*)&gB[(long)(s * 64 + prow4) * N + m0 + (mc + 2) * 32 + lslot * 8];
            }
            const int half = (mc & 1) * 4;
            const short8 af = *(const short8*)&Pwv[swzP(l15, mc * 4 + quad)];
            __builtin_amdgcn_s_setprio(1);
#pragma unroll
            for (int pj = 0; pj < 16; ++pj) {
                const short8 bg = *(const short8*)&Gs[swz64(pj * 16 + l15, half + quad)];
                oacc[pj] = __builtin_amdgcn_mfma_f32_16x16x32_bf16(af, bg, oacc[pj], 0, 0, 0);
            }
            __builtin_amdgcn_s_setprio(0);
            if (mc < 3) {
                const int wh = ((mc + 1) & 1) * 4;
#pragma unroll
                for (int s = 0; s < 4; ++s)
                    *(short8*)&Gs[swz64(s * 64 + prow4, wh + lslot)] = pg[(mc + 1) & 1][s];
                __syncthreads();
            }
        }
    }

    // ---- finalize: wave-private 1/l, write fp32 partial + (m,l) ----
    float linv[4];
#pragma unroll
    for (int r = 0; r < 4; ++r) linv[r] = 1.0f / lrun[r];
#pragma unroll
    for (int pj = 0; pj < 16; ++pj)
#pragma unroll
        for (int r = 0; r < 4; ++r) {
            const int row = q0 + wid * 16 + quad * 4 + r;
            const int col = pj * 16 + l15;
            ypB[(long)row * P + col] = oacc[pj][r] * linv[r];
        }
    if (l15 == 0) {
#pragma unroll
        for (int r = 0; r < 4; ++r) {
            const int row = q0 + wid * 16 + quad * 4 + r;
            mlB[row] = float2{mrun[r], lrun[r]};
        }
    }
}

// merge the four key-quarter partials: y = sum f_k*y_k, f_k = l_k e^{m_k-m}/Z
__global__ __launch_bounds__(256) void attn_merge(
    const float* __restrict__ yp, const float2* __restrict__ ml,
    unsigned short* __restrict__ ybf)
{
    const long STRIDE = 8L * 2048 * 256;
    const long NROWS  = 8L * 2048;
    const long t = (long)blockIdx.x * 256 + threadIdx.x;
    const long row = t >> 5;
    const int  c0  = ((int)t & 31) * 8;
    const float2 a0 = ml[row];
    const float2 a1 = ml[NROWS + row];
    const float2 a2 = ml[2 * NROWS + row];
    const float2 a3 = ml[3 * NROWS + row];
    const float mx = fmaxf(fmaxf(a0.x, a1.x), fmaxf(a2.x, a3.x));
    const float w0 = a0.y * __expf(a0.x - mx);
    const float w1 = a1.y * __expf(a1.x - mx);
    const float w2 = a2.y * __expf(a2.x - mx);
    const float w3 = a3.y * __expf(a3.x - mx);
    const float inv = 1.0f / (w0 + w1 + w2 + w3);
    const float f0 = w0 * inv, f1 = w1 * inv, f2 = w2 * inv, f3 = w3 * inv;
    const long base = row * 256 + c0;
    const float4 u0 = *(const float4*)&yp[base];
    const float4 u1 = *(const float4*)&yp[base + 4];
    const float4 v0 = *(const float4*)&yp[STRIDE + base];
    const float4 v1 = *(const float4*)&yp[STRIDE + base + 4];
    const float4 p0 = *(const float4*)&yp[2 * STRIDE + base];
    const float4 p1 = *(const float4*)&yp[2 * STRIDE + base + 4];
    const float4 q0 = *(const float4*)&yp[3 * STRIDE + base];
    const float4 q1 = *(const float4*)&yp[3 * STRIDE + base + 4];
    ushort4 o0, o1;
    o0.x = f2bf(f0 * u0.x + f1 * v0.x + f2 * p0.x + f3 * q0.x);
    o0.y = f2bf(f0 * u0.y + f1 * v0.y + f2 * p0.y + f3 * q0.y);
    o0.z = f2bf(f0 * u0.z + f1 * v0.z + f2 * p0.z + f3 * q0.z);
    o0.w = f2bf(f0 * u0.w + f1 * v0.w + f2 * p0.w + f3 * q0.w);
    o1.x = f2bf(f0 * u1.x + f1 * v1.x + f2 * p1.x + f3 * q1.x);
    o1.y = f2bf(f0 * u1.y + f1 * v1.y + f2 * p1.y + f3 * q1.y);
    o1.z = f2bf(f0 * u1.z + f1 * v1.z + f2 * p1.z + f3 * q1.z);
    o1.w = f2bf(f0 * u1.w + f1 * v1.w + f2 * p1.w + f3 * q1.w);
    *(ushort4*)&ybf[base] = o0;
    *(ushort4*)&ybf[base + 4] = o1;
}

// ---------------- BN finalize + apply ----------------
__global__ __launch_bounds__(256) void bn_finalize(
    const float* __restrict__ p1, const float* __restrict__ p2,
    float* __restrict__ mean, float* __restrict__ rstd, float cnt)
{
    const int c = blockIdx.x, t = threadIdx.x;
    __shared__ float rs[256], rq[256];
    rs[t] = p1[(long)c * 256 + t];
    rq[t] = p2[(long)c * 256 + t];
    __syncthreads();
    for (int st = 128; st > 0; st >>= 1) {
        if (t < st) { rs[t] += rs[t + st]; rq[t] += rq[t + st]; }
        __syncthreads();
    }
    if (t == 0) {
        const float m = rs[0] / cnt;
        mean[c] = m;
        rstd[c] = rsqrtf(rq[0] / cnt - m * m + 1e-5f);
    }
}

__global__ __launch_bounds__(256) void bn_apply_bf(
    const unsigned short* __restrict__ z, const float* __restrict__ x,
    const float* __restrict__ mean, const float* __restrict__ rstd,
    const float* __restrict__ gamma, const float* __restrict__ beta,
    float* __restrict__ out)
{
    const long i = ((long)blockIdx.x * 256 + threadIdx.x) * 8;
    const int c = (int)((i >> 11) & 511);    // (i / N) % C, N=2048, C=512
    const float mu = mean[c], rs = rstd[c], ga = gamma[c], be = beta[c];
    const ushort4 z0 = *(const ushort4*)&z[i];
    const ushort4 z1 = *(const ushort4*)&z[i + 4];
    const float4 x0 = *(const float4*)&x[i];
    const float4 x1 = *(const float4*)&x[i + 4];
    float4 o0, o1;
    o0.x = (bf2f(z0.x) - mu) * rs * ga + be + x0.x;
    o0.y = (bf2f(z0.y) - mu) * rs * ga + be + x0.y;
    o0.z = (bf2f(z0.z) - mu) * rs * ga + be + x0.z;
    o0.w = (bf2f(z0.w) - mu) * rs * ga + be + x0.w;
    o1.x = (bf2f(z1.x) - mu) * rs * ga + be + x1.x;
    o1.y = (bf2f(z1.y) - mu) * rs * ga + be + x1.y;
    o1.z = (bf2f(z1.z) - mu) * rs * ga + be + x1.z;
    o1.w = (bf2f(z1.w) - mu) * rs * ga + be + x1.w;
    *(float4*)&out[i] = o0;
    *(float4*)&out[i + 4] = o1;
}

extern "C" void kernel_launch(void* const* d_in, const int* in_sizes, int n_in,
                              void* d_out, int out_size, void* d_ws, size_t ws_size,
                              hipStream_t stream)
{
    const int B = 8, C = 512, N = 2048, P = 256;
    const float* x      = (const float*)d_in[0];
    const float* Wg     = (const float*)d_in[1];
    const float* Wtheta = (const float*)d_in[2];
    const float* Wphi   = (const float*)d_in[3];
    const float* Wz     = (const float*)d_in[4];
    const float* gamma  = (const float*)d_in[5];
    const float* beta   = (const float*)d_in[6];
    float* out = (float*)d_out;

    // ---- workspace layout (float units) ----
    float* ws = (float*)d_ws;
    const long NCle = (long)N * C;            // 1,048,576 per batch (= N*2P)
    const long NP   = (long)N * P;            // 524,288 per batch
    const long R0   = (long)B * NCle;         // 8.39M floats
    unsigned short* xtH   = (unsigned short*)ws;                // B*N*C
    unsigned short* xtL   = xtH + B * NCle;
    unsigned short* zbf   = (unsigned short*)ws;                // aliases xt (dead)
    unsigned short* thphH = (unsigned short*)(ws + R0);         // B*N*2P
    unsigned short* thphL = thphH + B * NCle;                   // B*N*2P
    unsigned short* gbf   = (unsigned short*)(ws + 2 * R0);     // B*P*N
    unsigned short* fbf   = gbf + B * NP;                       // attn partial region
    unsigned short* ybf   = fbf + (long)B * N * N;              // B*N*P
    unsigned short* W2H   = ybf + B * NP;                       // 2P*C
    unsigned short* W2L   = W2H + 2L * P * C;
    unsigned short* WgB   = W2L + 2L * P * C;                   // P*C
    unsigned short* WzB   = WgB + (long)P * C;
    // attn split-K partials: yp[4] exactly fills the dead fbf region
    // (4 * B*N*P floats == B*N*N shorts); ml lives in the dead xtL region.
    float*          yp    = (float*)fbf;                        // [4][B][N][P] fp32
    float2*         ml    = (float2*)(ws + 6L * 1024 * 1024);   // [4][B*N], in xtL
    // BN scratch aliases thph region (dead after fused_attn): [C][256] x2
    float*          bnp1  = ws + R0;
    float*          bnp2  = bnp1 + (long)C * 256;
    float*          mean  = bnp2 + (long)C * 256;
    float*          rstd  = mean + C;

    const long sX = (long)C * N;
    const int  P2 = 2 * P;

    // 1: transpose+split x -> xT hi/lo [B][N][C]
    transpose_split<<<dim3(N / 128, C / 32, B), 256, 0, stream>>>(x, xtH, xtL, C, N);
    // 2: fused weight prep (split_w2 + Wg/Wz casts), one launch
    prep_weights<<<(2 * P * C) / 256, 256, 0, stream>>>(
        Wtheta, Wphi, Wg, Wz, W2H, W2L, WgB, WzB, P * C);

    // 3: thph [B][N][2P] = xT @ W2^T (split in/out); XYSWAP grid
    mfma_gemm<true, 2, 4, 4, true><<<dim3(N / 128, P2 / 128, B), 256, 0, stream>>>(
        xtH, xtL, W2H, W2L, thphH, thphL, C, C, C, P2, NCle, 0, NCle, nullptr, nullptr);
    // 4: g [B][P][N] = Wg @ xT^T (plain, bf16 out); 64x128, 512 blocks
    mfma_gemm<false, 1, 2, 4, false><<<dim3(N / 128, P / 64, B), 256, 0, stream>>>(
        WgB, WgB, xtH, xtH, gbf, gbf, C, C, C, N, 0, NCle, NP, nullptr, nullptr);

    // 5: fused scores+softmax+y, split-K x4 (1024 blocks, 48KB -> 3/CU) + merge
    fused_attn<<<dim3(1024), 256, 0, stream>>>(thphH, thphL, gbf, yp, ml);
    attn_merge<<<dim3(2048), 256, 0, stream>>>(yp, ml, ybf);

    // 6: z [B][C][N] bf16 = Wz @ yT^T, BN partials (thph dead now)
    mfma_gemm<false, 3, 4, 4, false><<<dim3(N / 128, C / 128, B), 256, 0, stream>>>(
        WzB, WzB, ybf, ybf, zbf, zbf, P, P, P, N, 0, NP, sX, bnp1, bnp2);

    // 7: BN finalize + apply + residual
    bn_finalize<<<C, 256, 0, stream>>>(bnp1, bnp2, mean, rstd, (float)B * N);
    bn_apply_bf<<<(int)((B * sX) / 2048), 256, 0, stream>>>(zbf, x, mean, rstd, gamma, beta, out);
}

// Round 11
// 266.670 us; speedup vs baseline: 1.1809x; 1.1809x over previous
//
#include <hip/hip_runtime.h>
#include <hip/hip_bf16.h>

// B=8, C=512, N=2048, P=256.
// Round 21: lock in best-known config. R10 refuted the LDS-granularity
// occupancy theory (48KB exactly -> still 2 blocks/CU, fused 147us) —
// revert fused_attn to R9/R5 v5.1 (verified 100us), kh=2, square PV.
// Keep R10's prep_weights launch fusion (the one harmless piece).
// Ledger: R2 spill, R3 swizzle-neutral, R6 spill, R7 occupancy-cliff,
// R10 granule-refuted — the R5 structure is this family's optimum.
// Predicted: fused 101us (VGPR 128, LDS 50,688, FETCH 20.5MB, WRITE 33MB,
// Occ ~19.6, MfmaUtil ~28.5); total 314.9 -> ~263us.

typedef __attribute__((ext_vector_type(8))) short short8;
typedef __attribute__((ext_vector_type(4))) float floatx4;

// ---------------- bf16 helpers ----------------
__device__ __forceinline__ unsigned short f2bf(float v) {
    __hip_bfloat16 h = __float2bfloat16(v);
    return *(unsigned short*)&h;
}
__device__ __forceinline__ float bf2f(unsigned short u) {
    __hip_bfloat16 h;
    *(unsigned short*)&h = u;
    return __bfloat162float(h);
}

// async global->LDS 16B per lane (dest must be wave-linear: base + lane*16)
__device__ __forceinline__ void gl16(const unsigned short* g, unsigned short* l) {
    __builtin_amdgcn_global_load_lds(
        (const __attribute__((address_space(1))) unsigned int*)g,
        (__attribute__((address_space(3))) unsigned int*)l, 16, 0, 0);
}

// transpose + hi/lo split: X [R][N] fp32 -> Thi/Tlo [N][R] bf16 (batched over z)
// v2: 32r x 128n macro-tile, float4 loads, conflict-free LDS, short8 stores.
__global__ __launch_bounds__(256) void transpose_split(
    const float* __restrict__ X, unsigned short* __restrict__ Thi,
    unsigned short* __restrict__ Tlo, int R, int N)
{
    X   += (long)blockIdx.z * R * N;
    Thi += (long)blockIdx.z * N * R;
    Tlo += (long)blockIdx.z * N * R;
    __shared__ float s[32][133];
    const int t = threadIdx.x;
    const int n0 = blockIdx.x * 128, r0 = blockIdx.y * 32;
    const int nf = (t & 31) * 4, rf = t >> 5;
#pragma unroll
    for (int rr = 0; rr < 4; ++rr) {
        const int row = rf + rr * 8;
        const float4 v = *(const float4*)&X[(long)(r0 + row) * N + n0 + nf];
        s[row][nf]     = v.x;
        s[row][nf + 1] = v.y;
        s[row][nf + 2] = v.z;
        s[row][nf + 3] = v.w;
    }
    __syncthreads();
    const int n = t >> 1, rs = (t & 1) * 16;
    short8 h0, h1, l0, l1;
#pragma unroll
    for (int j = 0; j < 8; ++j) {
        const float v = s[rs + j][n];
        const unsigned short h = f2bf(v);
        h0[j] = (short)h;
        l0[j] = (short)f2bf(v - bf2f(h));
    }
#pragma unroll
    for (int j = 0; j < 8; ++j) {
        const float v = s[rs + 8 + j][n];
        const unsigned short h = f2bf(v);
        h1[j] = (short)h;
        l1[j] = (short)f2bf(v - bf2f(h));
    }
    const long ob = (long)(n0 + n) * R + r0 + rs;
    *(short8*)&Thi[ob]     = h0;
    *(short8*)&Thi[ob + 8] = h1;
    *(short8*)&Tlo[ob]     = l0;
    *(short8*)&Tlo[ob + 8] = l1;
}

// fused weight prep: [Wth;Wph] hi/lo split + Wg/Wz bf16 casts. grid = 2PC/256.
__global__ __launch_bounds__(256) void prep_weights(
    const float* __restrict__ Wth, const float* __restrict__ Wph,
    const float* __restrict__ Wg,  const float* __restrict__ Wz,
    unsigned short* __restrict__ Whi, unsigned short* __restrict__ Wlo,
    unsigned short* __restrict__ WgB, unsigned short* __restrict__ WzB, int PC)
{
    const int i = blockIdx.x * 256 + threadIdx.x;
    {
        const float v = (i < PC) ? Wth[i] : Wph[i - PC];
        const unsigned short hi = f2bf(v);
        Whi[i] = hi;
        Wlo[i] = f2bf(v - bf2f(hi));
    }
    if (i < PC / 4) {
        const float4 v = *(const float4*)&Wg[i * 4];
        ushort4 o;
        o.x = f2bf(v.x); o.y = f2bf(v.y); o.z = f2bf(v.z); o.w = f2bf(v.w);
        *(ushort4*)&WgB[i * 4] = o;
    } else if (i < PC / 2) {
        const int j = i - PC / 4;
        const float4 v = *(const float4*)&Wz[j * 4];
        ushort4 o;
        o.x = f2bf(v.x); o.y = f2bf(v.y); o.z = f2bf(v.z); o.w = f2bf(v.w);
        *(ushort4*)&WzB[j * 4] = o;
    }
}

// ---------------- MFMA GEMM (async global_load_lds, double-buffered) ----------
#define BK 32

template <bool SPLIT, int OUTMODE, int FM, int FN, bool XYSWAP>
__global__ __launch_bounds__(256) void mfma_gemm(
    const unsigned short* __restrict__ Ahi, const unsigned short* __restrict__ Alo,
    const unsigned short* __restrict__ Bhi, const unsigned short* __restrict__ Blo,
    void* __restrict__ Cout, void* __restrict__ Cout2,
    int K, int lda, int ldb, int ldc,
    long sA, long sB, long sC,
    float* __restrict__ S1, float* __restrict__ S2)
{
    constexpr int MTM = FM * 32, MTN = FN * 32;
    constexpr int SA = FM / 2, SB = FN / 2;
    constexpr int ASZ = MTM * BK, BSZ = MTN * BK;

    Ahi += (long)blockIdx.z * sA;
    Bhi += (long)blockIdx.z * sB;
    if (SPLIT) { Alo += (long)blockIdx.z * sA; Blo += (long)blockIdx.z * sB; }
    float* Cf = (float*)Cout + (long)blockIdx.z * sC;
    unsigned short* Ch = (unsigned short*)Cout + (long)blockIdx.z * sC;
    unsigned short* Cl = (unsigned short*)Cout2 + (long)blockIdx.z * sC;

    __shared__ unsigned short AsH[2 * ASZ], BsH[2 * BSZ];
    __shared__ unsigned short AsL[SPLIT ? 2 * ASZ : 8], BsL[SPLIT ? 2 * BSZ : 8];

    const int tid = threadIdx.x;
    const int wid = tid >> 6, lane = tid & 63;
    const int wm = (wid >> 1) * (FM * 16), wn = (wid & 1) * (FN * 16);
    const int l15 = lane & 15, quad = lane >> 4;
    const int m0 = (XYSWAP ? blockIdx.x : blockIdx.y) * MTM;
    const int n0 = (XYSWAP ? blockIdx.y : blockIdx.x) * MTN;

    int arow[SA], acol[SA], brow[SB], bcol[SB];
#pragma unroll
    for (int t = 0; t < SA; ++t) {
        const int gid = t * 256 + tid;
        arow[t] = gid >> 2; acol[t] = (gid & 3) * 8;
    }
#pragma unroll
    for (int t = 0; t < SB; ++t) {
        const int gid = t * 256 + tid;
        brow[t] = gid >> 2; bcol[t] = (gid & 3) * 8;
    }

    auto stage = [&](int k0, int buf) {
#pragma unroll
        for (int t = 0; t < SA; ++t) {
            const long o = (long)(m0 + arow[t]) * lda + k0 + acol[t];
            const int d = buf * ASZ + (t * 256 + tid) * 8;
            gl16(&Ahi[o], &AsH[d]);
            if (SPLIT) gl16(&Alo[o], &AsL[d]);
        }
#pragma unroll
        for (int t = 0; t < SB; ++t) {
            const long o = (long)(n0 + brow[t]) * ldb + k0 + bcol[t];
            const int d = buf * BSZ + (t * 256 + tid) * 8;
            gl16(&Bhi[o], &BsH[d]);
            if (SPLIT) gl16(&Blo[o], &BsL[d]);
        }
    };

    floatx4 acc[FM][FN];
#pragma unroll
    for (int i = 0; i < FM; ++i)
#pragma unroll
        for (int j = 0; j < FN; ++j) acc[i][j] = (floatx4){0.f, 0.f, 0.f, 0.f};

    const int iters = K / BK;
    stage(0, 0);
    __syncthreads();

    for (int it = 0; it < iters; ++it) {
        const int cur = it & 1;
        if (it + 1 < iters) stage((it + 1) * BK, cur ^ 1);

        short8 ah[FM], bh[FN], al[SPLIT ? FM : 1], bl[SPLIT ? FN : 1];
#pragma unroll
        for (int i = 0; i < FM; ++i) {
            ah[i] = *(const short8*)&AsH[cur * ASZ + (wm + i * 16 + l15) * BK + quad * 8];
            if (SPLIT) al[i] = *(const short8*)&AsL[cur * ASZ + (wm + i * 16 + l15) * BK + quad * 8];
        }
#pragma unroll
        for (int j = 0; j < FN; ++j) {
            bh[j] = *(const short8*)&BsH[cur * BSZ + (wn + j * 16 + l15) * BK + quad * 8];
            if (SPLIT) bl[j] = *(const short8*)&BsL[cur * BSZ + (wn + j * 16 + l15) * BK + quad * 8];
        }
#pragma unroll
        for (int i = 0; i < FM; ++i)
#pragma unroll
            for (int j = 0; j < FN; ++j) {
                acc[i][j] = __builtin_amdgcn_mfma_f32_16x16x32_bf16(ah[i], bh[j], acc[i][j], 0, 0, 0);
                if (SPLIT) {
                    acc[i][j] = __builtin_amdgcn_mfma_f32_16x16x32_bf16(ah[i], bl[j], acc[i][j], 0, 0, 0);
                    acc[i][j] = __builtin_amdgcn_mfma_f32_16x16x32_bf16(al[i], bh[j], acc[i][j], 0, 0, 0);
                }
            }

        __syncthreads();
    }

#pragma unroll
    for (int i = 0; i < FM; ++i)
#pragma unroll
        for (int j = 0; j < FN; ++j) {
            const int m = m0 + wm + i * 16 + quad * 4;
            const int n = n0 + wn + j * 16 + l15;
#pragma unroll
            for (int r = 0; r < 4; ++r) {
                const float v = acc[i][j][r];
                const long idx = (long)(m + r) * ldc + n;
                if (OUTMODE == 0) {
                    Cf[idx] = v;
                } else if (OUTMODE == 1 || OUTMODE == 3) {
                    Ch[idx] = f2bf(v);
                } else {
                    const unsigned short hi = f2bf(v);
                    Ch[idx] = hi;
                    Cl[idx] = f2bf(v - bf2f(hi));
                }
            }
        }

    if (OUTMODE == 3) {
        const int slot = (blockIdx.z * gridDim.x + blockIdx.x) * 2 + (wn >> 6);
#pragma unroll
        for (int i = 0; i < FM; ++i)
#pragma unroll
            for (int r = 0; r < 4; ++r) {
                float s = 0.f, q = 0.f;
#pragma unroll
                for (int j = 0; j < FN; ++j) {
                    const float v = acc[i][j][r];
                    s += v; q += v * v;
                }
#pragma unroll
                for (int msk = 1; msk < 16; msk <<= 1) {
                    s += __shfl_xor(s, msk, 64);
                    q += __shfl_xor(q, msk, 64);
                }
                if (l15 == 0) {
                    const int row = m0 + wm + i * 16 + quad * 4 + r;
                    S1[(long)row * 256 + slot] = s;
                    S2[(long)row * 256 + slot] = q;
                }
            }
    }
}

// ---------------- fused scores+softmax+y v5.1 (R5/R9 verified best) ------------
// 512 blocks (b = id&7, kh = (id>>3)&1, qt = id>>4), 4 waves.
// S phase: 8 chunks of 32 c; chunk kc lives in column-half kc&1 of the
//   [128][64]+swz64 phi tile; per chunk {gload kc+2 | MFMA kc | write kc+1}
//   then ONE barrier. PV: square tiling (64q x 64p/wave), 4 chunks of 32 keys.
// LDS: FG 32,768B (aliased phi/G) + Pw 17,408B + Aly 256B = 50,432B.
#define PSTRP 136   // P LDS row stride (128 keys + 8 pad)

// swizzled short-offset into a [rows][64-short] tile: 16B slot ^= row&7
__device__ __forceinline__ int swz64(int row, int slot) {
    return (row << 6) + (((slot ^ row) & 7) << 3);
}

__global__ __launch_bounds__(256, 2) void fused_attn(
    const unsigned short* __restrict__ thphH,
    const unsigned short* __restrict__ thphL,
    const unsigned short* __restrict__ gbf,
    float* __restrict__ yp,       // [2][B][N][P] fp32 partials (self-normalized)
    float2* __restrict__ ml)      // [2][B*N] {m, l}
{
    const int N = 2048, P = 256, P2 = 512;
    const int id = blockIdx.x;
    const int b  = id & 7;            // XCD-locality heuristic
    const int kh = (id >> 3) & 1;     // key half
    const int qt = id >> 4;           // 0..31
    const int q0 = qt * 64;

    const unsigned short* thB = thphH + (long)b * N * P2;
    const unsigned short* tlB = thphL + (long)b * N * P2;
    const unsigned short* gB  = gbf   + (long)b * P * N;
    float*  ypB = yp + (long)kh * (8L * N * P) + (long)b * N * P;
    float2* mlB = ml + (long)kh * (8L * N) + (long)b * N;

    // phi hi/lo and G share the same LDS (disjoint phases / halves, fenced)
    __shared__ unsigned short FG[2 * 128 * 64];       // 16,384 shorts = 32,768 B
    unsigned short* Fh = FG;                          // [128][64] swizzled
    unsigned short* Fl = FG + 128 * 64;
    unsigned short* Gs = FG;                          // [256][64] swizzled
    __shared__ unsigned short Pw[4][16 * PSTRP];      // per-rowgroup P (shared)
    __shared__ float Aly[64];                         // per-row alpha / linv

    const int tid = threadIdx.x;
    const int wid = tid >> 6, lane = tid & 63;
    const int l15 = lane & 15, quad = lane >> 4;

    // theta fragments in registers: wave rows [q0+wid*16, +16), A m = l15
    short8 tHr[8], tLr[8];
    {
        const unsigned short* t1 = thB + (long)(q0 + wid * 16 + l15) * P2;
        const unsigned short* t2 = tlB + (long)(q0 + wid * 16 + l15) * P2;
#pragma unroll
        for (int kt = 0; kt < 8; ++kt) {
            tHr[kt] = *(const short8*)&t1[kt * 32 + quad * 8];
            tLr[kt] = *(const short8*)&t2[kt * 32 + quad * 8];
        }
    }

    float mrun[4], lrun[4];
#pragma unroll
    for (int r = 0; r < 4; ++r) { mrun[r] = -1e30f; lrun[r] = 0.f; }

    // oacc[g*4+pj]: rows g*16+quad*4+r, cols wid*64+pj*16+l15
    floatx4 oacc[16];
#pragma unroll
    for (int p = 0; p < 16; ++p) oacc[p] = (floatx4){0.f, 0.f, 0.f, 0.f};

    // staging: prow4 = tid>>2 (0..63), lslot = tid&3 (16B granule in 32-short half)
    const int prow4 = tid >> 2, lslot = tid & 3;
    short8 pfH[2][2], pfL[2][2];   // [set][s], set = chunk&1 (static under unroll)
    short8 pg[2][4];

    for (int mt = 0; mt < 8; ++mt) {
        const int m0 = kh * 1024 + mt * 128;

        // ---- S phase: 8 chunks of 32 c, half-column dbuf ----
        floatx4 sacc[8];
#pragma unroll
        for (int j = 0; j < 8; ++j) sacc[j] = (floatx4){0.f, 0.f, 0.f, 0.f};

        // prologue: chunk0 -> half0, prefetch chunk1.
#pragma unroll
        for (int s = 0; s < 2; ++s) {
            const long o = (long)(m0 + s * 64 + prow4) * P2 + P + 0 * 32 + lslot * 8;
            pfH[0][s] = *(const short8*)&thB[o];
            pfL[0][s] = *(const short8*)&tlB[o];
        }
#pragma unroll
        for (int s = 0; s < 2; ++s) {
            const int row = s * 64 + prow4;
            *(short8*)&Fh[swz64(row, lslot)] = pfH[0][s];
            *(short8*)&Fl[swz64(row, lslot)] = pfL[0][s];
        }
#pragma unroll
        for (int s = 0; s < 2; ++s) {
            const long o = (long)(m0 + s * 64 + prow4) * P2 + P + 1 * 32 + lslot * 8;
            pfH[1][s] = *(const short8*)&thB[o];
            pfL[1][s] = *(const short8*)&tlB[o];
        }
        __syncthreads();

#pragma unroll
        for (int kc = 0; kc < 8; ++kc) {
            if (kc < 6) {                        // prefetch chunk kc+2 into set kc&1
#pragma unroll
                for (int s = 0; s < 2; ++s) {
                    const long o = (long)(m0 + s * 64 + prow4) * P2 + P + (kc + 2) * 32 + lslot * 8;
                    pfH[kc & 1][s] = *(const short8*)&thB[o];
                    pfL[kc & 1][s] = *(const short8*)&tlB[o];
                }
            }
            const short8 aH = tHr[kc];
            const short8 aL = tLr[kc];
            const int half = (kc & 1) * 4;
            __builtin_amdgcn_s_setprio(1);
#pragma unroll
            for (int j = 0; j < 8; ++j) {
                const int ro = swz64(j * 16 + l15, half + quad);
                const short8 bh = *(const short8*)&Fh[ro];
                const short8 bl = *(const short8*)&Fl[ro];
                sacc[j] = __builtin_amdgcn_mfma_f32_16x16x32_bf16(aH, bh, sacc[j], 0, 0, 0);
                sacc[j] = __builtin_amdgcn_mfma_f32_16x16x32_bf16(aH, bl, sacc[j], 0, 0, 0);
                sacc[j] = __builtin_amdgcn_mfma_f32_16x16x32_bf16(aL, bh, sacc[j], 0, 0, 0);
            }
            __builtin_amdgcn_s_setprio(0);
            if (kc < 7) {                        // write chunk kc+1 into other half
                const int wh = ((kc + 1) & 1) * 4;
#pragma unroll
                for (int s = 0; s < 2; ++s) {
                    const int row = s * 64 + prow4;
                    *(short8*)&Fh[swz64(row, wh + lslot)] = pfH[(kc + 1) & 1][s];
                    *(short8*)&Fl[swz64(row, wh + lslot)] = pfL[(kc + 1) & 1][s];
                }
            }
            __syncthreads();
        }

        // ---- online softmax (registers only; rows = quad*4+r) ----
        float alpha[4];
#pragma unroll
        for (int r = 0; r < 4; ++r) {
            float v = sacc[0][r];
#pragma unroll
            for (int j = 1; j < 8; ++j) v = fmaxf(v, sacc[j][r]);
            v = fmaxf(v, __shfl_xor(v, 1, 64));
            v = fmaxf(v, __shfl_xor(v, 2, 64));
            v = fmaxf(v, __shfl_xor(v, 4, 64));
            v = fmaxf(v, __shfl_xor(v, 8, 64));
            const float mo = mrun[r];
            const float mn = fmaxf(mo, v);
            mrun[r] = mn;
            alpha[r] = __expf(mo - mn);
        }
        float lpart[4] = {0.f, 0.f, 0.f, 0.f};
#pragma unroll
        for (int j = 0; j < 8; ++j)
#pragma unroll
            for (int r = 0; r < 4; ++r) {
                const float p = __expf(sacc[j][r] - mrun[r]);
                Pw[wid][(quad * 4 + r) * PSTRP + j * 16 + l15] = f2bf(p);
                lpart[r] += p;
            }
#pragma unroll
        for (int r = 0; r < 4; ++r) {
            float s = lpart[r];
            s += __shfl_xor(s, 1, 64);
            s += __shfl_xor(s, 2, 64);
            s += __shfl_xor(s, 4, 64);
            s += __shfl_xor(s, 8, 64);
            lrun[r] = lrun[r] * alpha[r] + s;
        }
        if (l15 == 0) {                    // publish row alphas for PV rescale
#pragma unroll
            for (int r = 0; r < 4; ++r) Aly[wid * 16 + quad * 4 + r] = alpha[r];
        }

        // ---- PV phase: square tiling, 4 chunks of 32 keys, half dbuf ----
#pragma unroll
        for (int s = 0; s < 4; ++s)
            pg[0][s] = *(const short8*)&gB[(long)(s * 64 + prow4) * N + m0 + 0 * 32 + lslot * 8];
#pragma unroll
        for (int s = 0; s < 4; ++s)
            *(short8*)&Gs[swz64(s * 64 + prow4, lslot)] = pg[0][s];
#pragma unroll
        for (int s = 0; s < 4; ++s)
            pg[1][s] = *(const short8*)&gB[(long)(s * 64 + prow4) * N + m0 + 1 * 32 + lslot * 8];
        __syncthreads();   // G0 + Pw + Aly visible

        float alr[4][4];
#pragma unroll
        for (int g = 0; g < 4; ++g)
#pragma unroll
            for (int r = 0; r < 4; ++r) alr[g][r] = Aly[g * 16 + quad * 4 + r];
        int noresc = 1;
#pragma unroll
        for (int g = 0; g < 4; ++g)
#pragma unroll
            for (int r = 0; r < 4; ++r) noresc &= (alr[g][r] == 1.f);
        if (!__all(noresc)) {
#pragma unroll
            for (int g = 0; g < 4; ++g)
#pragma unroll
                for (int pj = 0; pj < 4; ++pj)
#pragma unroll
                    for (int r = 0; r < 4; ++r) oacc[g * 4 + pj][r] *= alr[g][r];
        }

#pragma unroll
        for (int mc = 0; mc < 4; ++mc) {
            if (mc < 2) {                        // prefetch chunk mc+2 into set mc&1
#pragma unroll
                for (int s = 0; s < 4; ++s)
                    pg[mc & 1][s] = *(const short8*)&gB[(long)(s * 64 + prow4) * N + m0 + (mc + 2) * 32 + lslot * 8];
            }
            const int half = (mc & 1) * 4;
            short8 af[4];
#pragma unroll
            for (int g = 0; g < 4; ++g)
                af[g] = *(const short8*)&Pw[g][l15 * PSTRP + mc * 32 + quad * 8];
            __builtin_amdgcn_s_setprio(1);
#pragma unroll
            for (int pj = 0; pj < 4; ++pj) {
                const short8 bg = *(const short8*)&Gs[swz64(wid * 64 + pj * 16 + l15, half + quad)];
#pragma unroll
                for (int g = 0; g < 4; ++g)
                    oacc[g * 4 + pj] = __builtin_amdgcn_mfma_f32_16x16x32_bf16(af[g], bg, oacc[g * 4 + pj], 0, 0, 0);
            }
            __builtin_amdgcn_s_setprio(0);
            if (mc < 3) {                        // write chunk mc+1 into other half
                const int wh = ((mc + 1) & 1) * 4;
#pragma unroll
                for (int s = 0; s < 4; ++s)
                    *(short8*)&Gs[swz64(s * 64 + prow4, wh + lslot)] = pg[(mc + 1) & 1][s];
                __syncthreads();
            }
        }
    }

    // ---- finalize: publish 1/l, scale, write fp32 partial + (m,l) ----
    if (l15 == 0) {
#pragma unroll
        for (int r = 0; r < 4; ++r) Aly[wid * 16 + quad * 4 + r] = 1.0f / lrun[r];
    }
    __syncthreads();
    float liv[4][4];
#pragma unroll
    for (int g = 0; g < 4; ++g)
#pragma unroll
        for (int r = 0; r < 4; ++r) liv[g][r] = Aly[g * 16 + quad * 4 + r];
#pragma unroll
    for (int g = 0; g < 4; ++g)
#pragma unroll
        for (int pj = 0; pj < 4; ++pj)
#pragma unroll
            for (int r = 0; r < 4; ++r) {
                const int row = q0 + g * 16 + quad * 4 + r;
                const int col = wid * 64 + pj * 16 + l15;
                ypB[(long)row * P + col] = oacc[g * 4 + pj][r] * liv[g][r];
            }
    if (l15 == 0) {
#pragma unroll
        for (int r = 0; r < 4; ++r) {
            const int row = q0 + wid * 16 + quad * 4 + r;
            mlB[row] = float2{mrun[r], lrun[r]};
        }
    }
}

// merge the two key-half partials: y = f1*y1 + f2*y2, f_i = l_i e^{m_i-m}/Z
__global__ __launch_bounds__(256) void attn_merge(
    const float* __restrict__ yp, const float2* __restrict__ ml,
    unsigned short* __restrict__ ybf)
{
    const long HALF = 8L * 2048 * 256;
    const long t = (long)blockIdx.x * 256 + threadIdx.x;
    const long row = t >> 5;
    const int  c0  = ((int)t & 31) * 8;
    const float2 a = ml[row];
    const float2 c = ml[8L * 2048 + row];
    const float mx = fmaxf(a.x, c.x);
    const float w1 = a.y * __expf(a.x - mx);
    const float w2 = c.y * __expf(c.x - mx);
    const float inv = 1.0f / (w1 + w2);
    const float f1 = w1 * inv, f2 = w2 * inv;
    const long base = row * 256 + c0;
    const float4 u0 = *(const float4*)&yp[base];
    const float4 u1 = *(const float4*)&yp[base + 4];
    const float4 v0 = *(const float4*)&yp[HALF + base];
    const float4 v1 = *(const float4*)&yp[HALF + base + 4];
    ushort4 o0, o1;
    o0.x = f2bf(f1 * u0.x + f2 * v0.x);
    o0.y = f2bf(f1 * u0.y + f2 * v0.y);
    o0.z = f2bf(f1 * u0.z + f2 * v0.z);
    o0.w = f2bf(f1 * u0.w + f2 * v0.w);
    o1.x = f2bf(f1 * u1.x + f2 * v1.x);
    o1.y = f2bf(f1 * u1.y + f2 * v1.y);
    o1.z = f2bf(f1 * u1.z + f2 * v1.z);
    o1.w = f2bf(f1 * u1.w + f2 * v1.w);
    *(ushort4*)&ybf[base] = o0;
    *(ushort4*)&ybf[base + 4] = o1;
}

// ---------------- BN finalize + apply ----------------
__global__ __launch_bounds__(256) void bn_finalize(
    const float* __restrict__ p1, const float* __restrict__ p2,
    float* __restrict__ mean, float* __restrict__ rstd, float cnt)
{
    const int c = blockIdx.x, t = threadIdx.x;
    __shared__ float rs[256], rq[256];
    rs[t] = p1[(long)c * 256 + t];
    rq[t] = p2[(long)c * 256 + t];
    __syncthreads();
    for (int st = 128; st > 0; st >>= 1) {
        if (t < st) { rs[t] += rs[t + st]; rq[t] += rq[t + st]; }
        __syncthreads();
    }
    if (t == 0) {
        const float m = rs[0] / cnt;
        mean[c] = m;
        rstd[c] = rsqrtf(rq[0] / cnt - m * m + 1e-5f);
    }
}

__global__ __launch_bounds__(256) void bn_apply_bf(
    const unsigned short* __restrict__ z, const float* __restrict__ x,
    const float* __restrict__ mean, const float* __restrict__ rstd,
    const float* __restrict__ gamma, const float* __restrict__ beta,
    float* __restrict__ out)
{
    const long i = ((long)blockIdx.x * 256 + threadIdx.x) * 8;
    const int c = (int)((i >> 11) & 511);    // (i / N) % C, N=2048, C=512
    const float mu = mean[c], rs = rstd[c], ga = gamma[c], be = beta[c];
    const ushort4 z0 = *(const ushort4*)&z[i];
    const ushort4 z1 = *(const ushort4*)&z[i + 4];
    const float4 x0 = *(const float4*)&x[i];
    const float4 x1 = *(const float4*)&x[i + 4];
    float4 o0, o1;
    o0.x = (bf2f(z0.x) - mu) * rs * ga + be + x0.x;
    o0.y = (bf2f(z0.y) - mu) * rs * ga + be + x0.y;
    o0.z = (bf2f(z0.z) - mu) * rs * ga + be + x0.z;
    o0.w = (bf2f(z0.w) - mu) * rs * ga + be + x0.w;
    o1.x = (bf2f(z1.x) - mu) * rs * ga + be + x1.x;
    o1.y = (bf2f(z1.y) - mu) * rs * ga + be + x1.y;
    o1.z = (bf2f(z1.z) - mu) * rs * ga + be + x1.z;
    o1.w = (bf2f(z1.w) - mu) * rs * ga + be + x1.w;
    *(float4*)&out[i] = o0;
    *(float4*)&out[i + 4] = o1;
}

extern "C" void kernel_launch(void* const* d_in, const int* in_sizes, int n_in,
                              void* d_out, int out_size, void* d_ws, size_t ws_size,
                              hipStream_t stream)
{
    const int B = 8, C = 512, N = 2048, P = 256;
    const float* x      = (const float*)d_in[0];
    const float* Wg     = (const float*)d_in[1];
    const float* Wtheta = (const float*)d_in[2];
    const float* Wphi   = (const float*)d_in[3];
    const float* Wz     = (const float*)d_in[4];
    const float* gamma  = (const float*)d_in[5];
    const float* beta   = (const float*)d_in[6];
    float* out = (float*)d_out;

    // ---- workspace layout (float units) ----
    float* ws = (float*)d_ws;
    const long NCle = (long)N * C;            // 1,048,576 per batch (= N*2P)
    const long NP   = (long)N * P;            // 524,288 per batch
    const long R0   = (long)B * NCle;         // 8.39M floats
    unsigned short* xtH   = (unsigned short*)ws;                // B*N*C
    unsigned short* xtL   = xtH + B * NCle;
    unsigned short* zbf   = (unsigned short*)ws;                // aliases xt (dead)
    unsigned short* thphH = (unsigned short*)(ws + R0);         // B*N*2P
    unsigned short* thphL = thphH + B * NCle;                   // B*N*2P
    unsigned short* gbf   = (unsigned short*)(ws + 2 * R0);     // B*P*N
    unsigned short* fbf   = gbf + B * NP;                       // attn partial region
    unsigned short* ybf   = fbf + (long)B * N * N;              // B*N*P
    unsigned short* W2H   = ybf + B * NP;                       // 2P*C
    unsigned short* W2L   = W2H + 2L * P * C;
    unsigned short* WgB   = W2L + 2L * P * C;                   // P*C
    unsigned short* WzB   = WgB + (long)P * C;
    // attn split-K partials in the dead fbf region; ml in dead xtL region.
    float*          yp    = (float*)fbf;                        // [2][B][N][P] fp32
    float2*         ml    = (float2*)(ws + 6L * 1024 * 1024);   // [2][B*N], in xtL
    // BN scratch aliases thph region (dead after fused_attn): [C][256] x2
    float*          bnp1  = ws + R0;
    float*          bnp2  = bnp1 + (long)C * 256;
    float*          mean  = bnp2 + (long)C * 256;
    float*          rstd  = mean + C;

    const long sX = (long)C * N;
    const int  P2 = 2 * P;

    // 1: transpose+split x -> xT hi/lo [B][N][C]
    transpose_split<<<dim3(N / 128, C / 32, B), 256, 0, stream>>>(x, xtH, xtL, C, N);
    // 2: fused weight prep (split_w2 + Wg/Wz casts), one launch
    prep_weights<<<(2 * P * C) / 256, 256, 0, stream>>>(
        Wtheta, Wphi, Wg, Wz, W2H, W2L, WgB, WzB, P * C);

    // 3: thph [B][N][2P] = xT @ W2^T (split in/out); XYSWAP grid
    mfma_gemm<true, 2, 4, 4, true><<<dim3(N / 128, P2 / 128, B), 256, 0, stream>>>(
        xtH, xtL, W2H, W2L, thphH, thphL, C, C, C, P2, NCle, 0, NCle, nullptr, nullptr);
    // 4: g [B][P][N] = Wg @ xT^T (plain, bf16 out); 64x128, 512 blocks
    mfma_gemm<false, 1, 2, 4, false><<<dim3(N / 128, P / 64, B), 256, 0, stream>>>(
        WgB, WgB, xtH, xtH, gbf, gbf, C, C, C, N, 0, NCle, NP, nullptr, nullptr);

    // 5: fused scores+softmax+y, split-K x2 over keys (512 blocks, 2/CU) + merge
    fused_attn<<<dim3(512), 256, 0, stream>>>(thphH, thphL, gbf, yp, ml);
    attn_merge<<<dim3(2048), 256, 0, stream>>>(yp, ml, ybf);

    // 6: z [B][C][N] bf16 = Wz @ yT^T, BN partials (thph dead now)
    mfma_gemm<false, 3, 4, 4, false><<<dim3(N / 128, C / 128, B), 256, 0, stream>>>(
        WzB, WzB, ybf, ybf, zbf, zbf, P, P, P, N, 0, NP, sX, bnp1, bnp2);

    // 7: BN finalize + apply + residual
    bn_finalize<<<C, 256, 0, stream>>>(bnp1, bnp2, mean, rstd, (float)B * N);
    bn_apply_bf<<<(int)((B * sX) / 2048), 256, 0, stream>>>(zbf, x, mean, rstd, gamma, beta, out);
}